// Round 9
// baseline (179.756 us; speedup 1.0000x reference)
//
#include <hip/hip_runtime.h>
#include <hip/hip_bf16.h>

using u16 = unsigned short;
using u32 = unsigned int;

typedef __bf16 bf16x8 __attribute__((ext_vector_type(8)));
typedef float f32x4 __attribute__((ext_vector_type(4)));

__device__ __forceinline__ u16 f2bf(float f) {
  union { float f; u32 u; } c; c.f = f;
  u32 u = c.u;
  u32 r = u + 0x7fffu + ((u >> 16) & 1u);   // RNE
  return (u16)(r >> 16);
}
__device__ __forceinline__ u32 pack2(float a, float b) {
  return (u32)f2bf(a) | ((u32)f2bf(b) << 16);
}

constexpr int Bb  = 64;    // graphs
constexpr int L   = 1024;  // nodes/graph
constexpr int IN  = 128;
constexpr int OUT = 128;
constexpr int FLR = 64;
constexpr int N   = Bb * L;

// ---------------------------------------------------------------------------
// k_pack: block 0 packs W_out[256][128] into MFMA B-frag order (for k_fused),
// block 1 packs Wh[128][64] into MFMA B-frag order (for k_sh).
// Frag layout (16x16x32): elem j of lane = W[kstep*32+(lane>>4)*8+j][nt*16+(lane&15)]
// ---------------------------------------------------------------------------
__global__ __launch_bounds__(256) void k_pack(
    const float* __restrict__ Wout, const float* __restrict__ Wh,
    u16* __restrict__ Bp, u16* __restrict__ Whp)
{
  if (blockIdx.x == 0) {
#pragma unroll
    for (int it = 0; it < 16; ++it) {
      int t2 = it * 256 + threadIdx.x;     // 4096 frag-lanes (8 nt x 8 ks x 64)
      int lane = t2 & 63, kstep = (t2 >> 6) & 7, ntile = t2 >> 9;
      int n  = ntile * 16 + (lane & 15);
      int kb = kstep * 32 + (lane >> 4) * 8;
      u16* dst = Bp + (size_t)t2 * 8;
#pragma unroll
      for (int j = 0; j < 8; ++j) dst[j] = f2bf(Wout[(kb + j) * OUT + n]);
    }
  } else {
#pragma unroll
    for (int it = 0; it < 4; ++it) {
      int t2 = it * 256 + threadIdx.x;     // 1024 frag-lanes (4 nt x 4 ks x 64)
      int lane = t2 & 63, kstep = (t2 >> 6) & 3, ntile = t2 >> 8;
      int n  = ntile * 16 + (lane & 15);
      int kb = kstep * 32 + (lane >> 4) * 8;
      u16* dst = Whp + (size_t)t2 * 8;
#pragma unroll
      for (int j = 0; j < 8; ++j) dst[j] = f2bf(Wh[(kb + j) * FLR + n]);
    }
  }
}

// ---------------------------------------------------------------------------
// k_sh: blocks of 256 (4 waves), 64 nodes each; wave w = one 16-row MFMA
// m-tile. h = x@Wh+bh via 16 MFMAs/wave with pre-packed B-frags (Whp,
// contiguous dwordx4/lane). s = x@Ws+bs fp32 with butterfly reduce.
// Also writes snorm = 0.5*|s|^2 for the norm-expansion scan.
// ---------------------------------------------------------------------------
__global__ __launch_bounds__(256) void k_sh(
    const float* __restrict__ x, const float* __restrict__ Ws, const float* __restrict__ bs,
    const u16* __restrict__ Whp, const float* __restrict__ bh,
    float* __restrict__ s_buf, float* __restrict__ snorm, u16* __restrict__ h_buf)
{
  const int lane = threadIdx.x & 63;
  const int w = __builtin_amdgcn_readfirstlane(threadIdx.x >> 6);
  const int mb = blockIdx.x * 64 + w * 16;
  const int col = lane & 15;
  const int kq  = lane >> 4;               // 0..3
  const int mrow = mb + col;
  const float* xr = x + (size_t)mrow * IN;

  // ---- load x A-frags (fp32->bf16) + accumulate s partials in fp32
  float sp0 = 0.f, sp1 = 0.f, sp2 = 0.f, sp3 = 0.f;
  bf16x8 a[4];
#pragma unroll
  for (int ks = 0; ks < 4; ++ks) {
    float4 xa = *(const float4*)(xr + ks * 32 + kq * 8);
    float4 xb = *(const float4*)(xr + ks * 32 + kq * 8 + 4);
    float xf[8] = {xa.x, xa.y, xa.z, xa.w, xb.x, xb.y, xb.z, xb.w};
#pragma unroll
    for (int j = 0; j < 8; ++j) {
      const float4 wsr = *(const float4*)(Ws + (size_t)(ks * 32 + kq * 8 + j) * 4);
      sp0 = fmaf(xf[j], wsr.x, sp0);
      sp1 = fmaf(xf[j], wsr.y, sp1);
      sp2 = fmaf(xf[j], wsr.z, sp2);
      sp3 = fmaf(xf[j], wsr.w, sp3);
    }
    union { __hip_bfloat162 h2[4]; bf16x8 v; } cv;
    cv.h2[0] = __float22bfloat162_rn(float2{xf[0], xf[1]});
    cv.h2[1] = __float22bfloat162_rn(float2{xf[2], xf[3]});
    cv.h2[2] = __float22bfloat162_rn(float2{xf[4], xf[5]});
    cv.h2[3] = __float22bfloat162_rn(float2{xf[6], xf[7]});
    a[ks] = cv.v;
  }

  // ---- h GEMM: 4 n-tiles x 4 k-steps; B-frags pre-packed (contiguous)
  f32x4 acc[4];
#pragma unroll
  for (int nt = 0; nt < 4; ++nt) acc[nt] = f32x4{0.f, 0.f, 0.f, 0.f};
  const bf16x8* __restrict__ whp = (const bf16x8*)Whp;
#pragma unroll
  for (int nt = 0; nt < 4; ++nt) {
#pragma unroll
    for (int ks = 0; ks < 4; ++ks) {
      bf16x8 bv = whp[(nt * 4 + ks) * 64 + lane];
      acc[nt] = __builtin_amdgcn_mfma_f32_16x16x32_bf16(a[ks], bv, acc[nt], 0, 0, 0);
    }
  }

  // ---- s reduce + store (fp32) + snorm
  sp0 += __shfl_xor(sp0, 16, 64); sp0 += __shfl_xor(sp0, 32, 64);
  sp1 += __shfl_xor(sp1, 16, 64); sp1 += __shfl_xor(sp1, 32, 64);
  sp2 += __shfl_xor(sp2, 16, 64); sp2 += __shfl_xor(sp2, 32, 64);
  sp3 += __shfl_xor(sp3, 16, 64); sp3 += __shfl_xor(sp3, 32, 64);
  if (kq == 0) {
    float4 sv;
    sv.x = sp0 + bs[0]; sv.y = sp1 + bs[1];
    sv.z = sp2 + bs[2]; sv.w = sp3 + bs[3];
    *(float4*)(s_buf + (size_t)mrow * 4) = sv;
    snorm[mrow] = 0.5f * (sv.x * sv.x + sv.y * sv.y + sv.z * sv.z + sv.w * sv.w);
  }

  // ---- h epilogue: bias + bf16 store (C-layout: col=lane&15, row=kq*4+r)
#pragma unroll
  for (int nt = 0; nt < 4; ++nt) {
    float bias = bh[nt * 16 + col];
#pragma unroll
    for (int r = 0; r < 4; ++r) {
      float v = acc[nt][r] + bias;
      h_buf[(size_t)(mb + kq * 4 + r) * FLR + nt * 16 + col] = f2bf(v);
    }
  }
}

// ---------------------------------------------------------------------------
// k_fused: knn select + aggregate + output GEMM; block = 512 thr (8 waves)
// per 64 nodes of one graph.
//   stage: graph's 1024 s-vectors + half-norms -> LDS (aliased over lists).
//   scan:  wave w scans [w*128,(w+1)*128) from LDS (broadcast ds_reads);
//          key = trunc10(max(0, ci+nj-si.sj))|j  == d2/2, ties->lower j.
//   merge: 3-level bitonic min-identity tree -> fk.
//   agg:   lane=(nb,q); uint4 gather of h; mean/max via 3 shfl_xor; -> LDS.
//   gemm:  A ks<4 from fp32 x (in-register cvt), ks>=4 from LDS agg; B=Bp.
// ---------------------------------------------------------------------------
__global__ __launch_bounds__(512) void k_fused(
    const float* __restrict__ s_buf, const float* __restrict__ snorm,
    const u16* __restrict__ h_buf, const float* __restrict__ x,
    const u16* __restrict__ Bp, const float* __restrict__ bout,
    float* __restrict__ out)
{
  __shared__ alignas(16) float lists[8 * 64 * 17];   // 34.8 KB; s-tile, then lists, then agg
  __shared__ float fk[64 * 17];
  u16* agg_lds = (u16*)lists;                        // [64][136] bf16 (post-merge)
  float4* s_lds = (float4*)lists;                    // [1024] float4 (pre-merge)
  float*  n_lds = lists + 4096;                      // [1024] floats

  const int t = threadIdx.x;
  const int lane = t & 63;
  const int w = __builtin_amdgcn_readfirstlane(t >> 6);
  const int g = blockIdx.y;
  const int nb0 = blockIdx.x * 64;

  // ---- stage s + norms into LDS (coalesced, 2 nodes/thread)
  {
    const float4* sg = (const float4*)(s_buf + (size_t)g * L * 4);
    const float* sn = snorm + (size_t)g * L;
#pragma unroll
    for (int i = 0; i < 2; ++i) {
      int j = i * 512 + t;
      s_lds[j] = sg[j];
      n_lds[j] = sn[j];
    }
  }
  __syncthreads();

  const float4 si = s_lds[nb0 + lane];
  const float ci = n_lds[nb0 + lane];
  const int jb = __builtin_amdgcn_readfirstlane(w * 128);

  float b[16];
#pragma unroll
  for (int k = 0; k < 16; ++k) b[k] = 3.0e38f;

#pragma unroll 8
  for (int j = 0; j < 128; ++j) {
    float4 sjv = s_lds[jb + j];          // wave-uniform -> LDS broadcast
    float cnj = ci + n_lds[jb + j];
    float d = fmaf(si.x, -sjv.x, cnj);
    d = fmaf(si.y, -sjv.y, d);
    d = fmaf(si.z, -sjv.z, d);
    d = fmaf(si.w, -sjv.w, d);
    d = fmaxf(d, 0.0f);                  // d2/2; clamp keeps self-pair first
    u32 db = __float_as_uint(d);
    float key = __uint_as_float((db & 0xFFFFFC00u) | (u32)(jb + j));
#pragma unroll
    for (int k = 15; k >= 1; --k) b[k] = __builtin_amdgcn_fmed3f(key, b[k - 1], b[k]);
    b[0] = fminf(key, b[0]);
  }
  __syncthreads();   // all scans done before lists overwrite s-tile

#pragma unroll
  for (int k = 0; k < 16; ++k) lists[(w * 64 + lane) * 17 + k] = b[k];
  __syncthreads();

  float c[16];
  // level 1: w<4 merges (w, w+4)
  if (w < 4) {
#pragma unroll
    for (int i = 0; i < 16; ++i)
      c[i] = fminf(b[i], lists[((w + 4) * 64 + lane) * 17 + (15 - i)]);
#pragma unroll
    for (int dd = 8; dd >= 1; dd >>= 1) {
#pragma unroll
      for (int i = 0; i < 16; ++i) {
        if ((i & dd) == 0) {
          float lo = fminf(c[i], c[i | dd]);
          float hi = fmaxf(c[i], c[i | dd]);
          c[i] = lo; c[i | dd] = hi;
        }
      }
    }
#pragma unroll
    for (int k = 0; k < 16; ++k) lists[(w * 64 + lane) * 17 + k] = c[k];
  }
  __syncthreads();
  // level 2: w<2 merges (w, w+2)
  if (w < 2) {
#pragma unroll
    for (int i = 0; i < 16; ++i)
      c[i] = fminf(c[i], lists[((w + 2) * 64 + lane) * 17 + (15 - i)]);
#pragma unroll
    for (int dd = 8; dd >= 1; dd >>= 1) {
#pragma unroll
      for (int i = 0; i < 16; ++i) {
        if ((i & dd) == 0) {
          float lo = fminf(c[i], c[i | dd]);
          float hi = fmaxf(c[i], c[i | dd]);
          c[i] = lo; c[i | dd] = hi;
        }
      }
    }
#pragma unroll
    for (int k = 0; k < 16; ++k) lists[(w * 64 + lane) * 17 + k] = c[k];
  }
  __syncthreads();
  // level 3: w==0, set-only (order-free downstream)
  if (w == 0) {
#pragma unroll
    for (int i = 0; i < 16; ++i) {
      float o = lists[(64 + lane) * 17 + (15 - i)];
      fk[lane * 17 + i] = fminf(c[i], o);
    }
  }
  __syncthreads();        // fk ready; lists dead -> agg_lds

  // ---- aggregation: wave w -> block-local nodes [w*8, w*8+8)
  const int q  = lane & 7;
  const int nb = lane >> 3;
  const u16* __restrict__ hg = h_buf + (size_t)g * L * FLR;

#pragma unroll 2
  for (int tt = 0; tt < 8; ++tt) {
    const int nodeL = w * 8 + tt;
    float k1 = fk[nodeL * 17 + nb];
    float k2 = fk[nodeL * 17 + 8 + nb];
    u32 u1 = __float_as_uint(k1), u2 = __float_as_uint(k2);
    float w1 = __expf(-20.0f * __uint_as_float(u1 & 0xFFFFFC00u));  // key = d2/2
    float w2 = __expf(-20.0f * __uint_as_float(u2 & 0xFFFFFC00u));
    const uint4 av = ((const uint4*)(hg + (size_t)(u1 & 1023u) * FLR))[q];
    const uint4 bv = ((const uint4*)(hg + (size_t)(u2 & 1023u) * FLR))[q];
    u32 pa[4] = {av.x, av.y, av.z, av.w};
    u32 pb[4] = {bv.x, bv.y, bv.z, bv.w};
    float m[8], xx[8];
#pragma unroll
    for (int d = 0; d < 4; ++d) {
      float a0 = __uint_as_float(pa[d] << 16) * w1;
      float a1 = __uint_as_float(pa[d] & 0xFFFF0000u) * w1;
      float b0 = __uint_as_float(pb[d] << 16) * w2;
      float b1 = __uint_as_float(pb[d] & 0xFFFF0000u) * w2;
      m[2 * d]     = a0 + b0;  xx[2 * d]     = fmaxf(a0, b0);
      m[2 * d + 1] = a1 + b1;  xx[2 * d + 1] = fmaxf(a1, b1);
    }
#pragma unroll
    for (int mask = 8; mask <= 32; mask <<= 1) {
#pragma unroll
      for (int jj = 0; jj < 8; ++jj) m[jj] += __shfl_xor(m[jj], mask, 64);
#pragma unroll
      for (int jj = 0; jj < 8; ++jj) xx[jj] = fmaxf(xx[jj], __shfl_xor(xx[jj], mask, 64));
    }
    if (nb == 0) {
      uint4 o;
      o.x = pack2(m[0] * 0.0625f, m[1] * 0.0625f);
      o.y = pack2(m[2] * 0.0625f, m[3] * 0.0625f);
      o.z = pack2(m[4] * 0.0625f, m[5] * 0.0625f);
      o.w = pack2(m[6] * 0.0625f, m[7] * 0.0625f);
      *(uint4*)(&agg_lds[nodeL * 136 + q * 8]) = o;
    } else if (nb == 1) {
      uint4 o;
      o.x = pack2(xx[0], xx[1]); o.y = pack2(xx[2], xx[3]);
      o.z = pack2(xx[4], xx[5]); o.w = pack2(xx[6], xx[7]);
      *(uint4*)(&agg_lds[nodeL * 136 + FLR + q * 8]) = o;
    }
  }
  __syncthreads();

  // ---- output GEMM: wave w = m-tile (w&3) x nt-half (w>>2)
  const int mt  = w & 3;
  const int ntb = (w >> 2) * 4;
  const int rowL = mt * 16 + (lane & 15);
  const int grow = g * L + nb0 + rowL;
  const int kq = (lane >> 4) * 8;

  f32x4 acc[4];
#pragma unroll
  for (int nt = 0; nt < 4; ++nt) acc[nt] = f32x4{0.f, 0.f, 0.f, 0.f};

  const float* xr = x + (size_t)grow * IN;
  const bf16x8* __restrict__ bp = (const bf16x8*)Bp;

#pragma unroll
  for (int ks = 0; ks < 8; ++ks) {
    bf16x8 a;
    if (ks < 4) {
      float4 xa = *(const float4*)(xr + ks * 32 + kq);
      float4 xb = *(const float4*)(xr + ks * 32 + kq + 4);
      union { __hip_bfloat162 h2[4]; bf16x8 v; } cv;
      cv.h2[0] = __float22bfloat162_rn(float2{xa.x, xa.y});
      cv.h2[1] = __float22bfloat162_rn(float2{xa.z, xa.w});
      cv.h2[2] = __float22bfloat162_rn(float2{xb.x, xb.y});
      cv.h2[3] = __float22bfloat162_rn(float2{xb.z, xb.w});
      a = cv.v;
    } else {
      a = *(const bf16x8*)(&agg_lds[rowL * 136 + (ks - 4) * 32 + kq]);
    }
#pragma unroll
    for (int nt = 0; nt < 4; ++nt) {
      bf16x8 bb = bp[((ntb + nt) * 8 + ks) * 64 + lane];
      acc[nt] = __builtin_amdgcn_mfma_f32_16x16x32_bf16(a, bb, acc[nt], 0, 0, 0);
    }
  }

  const int rbase = (lane >> 4) * 4;
  const int col = lane & 15;
  const int mrow = g * L + nb0 + mt * 16;
#pragma unroll
  for (int nt = 0; nt < 4; ++nt) {
    float bias = bout[(ntb + nt) * 16 + col];
#pragma unroll
    for (int r = 0; r < 4; ++r) {
      float v = acc[nt][r] + bias;
      out[(size_t)(mrow + rbase + r) * OUT + (ntb + nt) * 16 + col] = fmaxf(v, 0.0f);
    }
  }
}

extern "C" void kernel_launch(void* const* d_in, const int* in_sizes, int n_in,
                              void* d_out, int out_size, void* d_ws, size_t ws_size,
                              hipStream_t stream) {
  const float* x    = (const float*)d_in[0];
  const float* Ws   = (const float*)d_in[1];
  const float* bs   = (const float*)d_in[2];
  const float* Wh   = (const float*)d_in[3];
  const float* bh   = (const float*)d_in[4];
  const float* Wout = (const float*)d_in[5];
  const float* bout = (const float*)d_in[6];
  float* out = (float*)d_out;

  char* ws = (char*)d_ws;
  float* s_buf = (float*)ws;                                     // 1 MiB
  float* snorm = (float*)(ws + (1 << 20));                       // 256 KiB
  u16*   h_buf = (u16*)(ws + (1 << 20) + (1 << 18));             // 8 MiB
  u16*   Bp    = (u16*)(ws + (1 << 20) + (1 << 18) + (8 << 20)); // 64 KiB
  u16*   Whp   = (u16*)(ws + (1 << 20) + (1 << 18) + (8 << 20) + (1 << 16)); // 16 KiB

  k_pack<<<2, 256, 0, stream>>>(Wout, Wh, Bp, Whp);
  k_sh<<<N / 64, 256, 0, stream>>>(x, Ws, bs, Whp, bh, s_buf, snorm, h_buf);
  dim3 gknn(L / 64, Bb);
  k_fused<<<gknn, 512, 0, stream>>>(s_buf, snorm, h_buf, x, Bp, bout, out);
}